// Round 3
// baseline (660.151 us; speedup 1.0000x reference)
//
#include <hip/hip_runtime.h>
#include <hip/hip_bf16.h>
#include <stdint.h>

// Problem constants (B,L,D,H,UNITS = 64,1024,1024,1024,1024)
#define B_ 64
#define L_ 1024
#define D_ 1024
#define U_ 1024
#define M_ (B_ * L_)  // 65536 rows of the big GEMM

typedef __attribute__((ext_vector_type(8))) __bf16 bf16x8;
typedef __attribute__((ext_vector_type(4))) float f32x4;
typedef __attribute__((ext_vector_type(8))) unsigned short u16x8;

// fp32 -> bf16 with round-to-nearest-even
__device__ __forceinline__ unsigned short f2bf(float f) {
  unsigned u = __float_as_uint(f);
  unsigned r = (u + 0x7fffu + ((u >> 16) & 1u)) >> 16;
  return (unsigned short)r;
}

__device__ __forceinline__ float bf2f(unsigned short h) {
  return __uint_as_float(((unsigned)h) << 16);
}

// async global->LDS, 16B per lane. LDS dest must be wave-uniform base; HW adds lane*16.
__device__ __forceinline__ void async_copy16(const void* gptr, void* ldsptr) {
  __builtin_amdgcn_global_load_lds(
      (const __attribute__((address_space(1))) void*)gptr,
      (__attribute__((address_space(3))) void*)ldsptr,
      16, 0, 0);
}

// ---------------------------------------------------------------------------
// Kernel 1: features fp32 [M][D] -> bf16 [M][D]
// grid-stride, 32B load + 16B store per iteration (was: 1 elem/thread,
// 262K waves of launch overhead -> ~1.5 TB/s effective)
// ---------------------------------------------------------------------------
__global__ __launch_bounds__(256) void convert_f_bf16(
    const float4* __restrict__ src, u16x8* __restrict__ dst) {
  const long n8 = (long)M_ * D_ / 8;  // 8388608 ushort8 elements
  for (long i = (long)blockIdx.x * 256 + threadIdx.x; i < n8;
       i += (long)gridDim.x * 256) {
    float4 a = src[2 * i];
    float4 b = src[2 * i + 1];
    u16x8 o;
    o[0] = f2bf(a.x); o[1] = f2bf(a.y); o[2] = f2bf(a.z); o[3] = f2bf(a.w);
    o[4] = f2bf(b.x); o[5] = f2bf(b.y); o[6] = f2bf(b.z); o[7] = f2bf(b.w);
    dst[i] = o;
  }
}

// ---------------------------------------------------------------------------
// Kernel 2: W1 [D][U] fp32 -> W1T [U][D] bf16 (so B-fragments are K-contiguous)
// ---------------------------------------------------------------------------
__global__ __launch_bounds__(256) void transpose_w1(
    const float* __restrict__ W1, unsigned short* __restrict__ W1T) {
  __shared__ float tile[32][33];
  int tx = threadIdx.x & 31, ty = threadIdx.x >> 5;  // (32,8)
  int u0 = blockIdx.x * 32, k0 = blockIdx.y * 32;
#pragma unroll
  for (int i = ty; i < 32; i += 8) tile[i][tx] = W1[(long)(k0 + i) * U_ + u0 + tx];
  __syncthreads();
#pragma unroll
  for (int i = ty; i < 32; i += 8)
    W1T[(long)(u0 + i) * D_ + k0 + tx] = f2bf(tile[tx][i]);
}

// ---------------------------------------------------------------------------
// Kernel 3: ph[b][u] = hidden[b][:] @ W2[:][u] + b1[u] + b2[u]   (fp32 exact)
// grid (4 u-tiles, 8 b-groups, 8 h-chunks). Hidden slice (8 b x 128 h) staged
// in LDS once; the h-loop then only streams W2 with unroll-8 ILP (was: 128
// serialized dependent W2 loads at 4 waves/CU ~= 50 us latency-bound).
// ---------------------------------------------------------------------------
__global__ __launch_bounds__(256) void proj_h_kernel(
    const float* __restrict__ hidden, const float* __restrict__ W2,
    const float* __restrict__ b1, const float* __restrict__ b2,
    float* __restrict__ ph) {
  __shared__ float hs[8][128];
  int u = blockIdx.x * 256 + threadIdx.x;
  int bbase = blockIdx.y * 8;
  int h0 = blockIdx.z * 128;

  {  // stage hidden[bbase..+8][h0..+128] -> LDS (4KB), float4 per thread
    int base = threadIdx.x * 4;
    int row = base >> 7, col = base & 127;
    float4 v = *(const float4*)&hidden[(long)(bbase + row) * 1024 + h0 + col];
    *(float4*)&hs[row][col] = v;
  }
  __syncthreads();

  float acc[8];
  float bias = (blockIdx.z == 0) ? (b1[u] + b2[u]) : 0.0f;
#pragma unroll
  for (int i = 0; i < 8; ++i) acc[i] = bias;
#pragma unroll 8
  for (int h = 0; h < 128; ++h) {
    float w = W2[(long)(h0 + h) * U_ + u];
#pragma unroll
    for (int i = 0; i < 8; ++i) acc[i] += hs[i][h] * w;
  }
#pragma unroll
  for (int i = 0; i < 8; ++i) atomicAdd(&ph[(bbase + i) * U_ + u], acc[i]);
}

// ---------------------------------------------------------------------------
// Kernel 4: fused  logits[m] += sum_u tanh(A@W1 + ph) * V[u]
// m97 structure: 128x128 tile, BK=32, 4 waves (2x2), 4x4 16x16x32 MFMA per wave,
// global_load_lds dwordx4 staging, unpadded [row][k] LDS tiles.
// 1D grid 4096 with XCD-aware decode (R1: FETCH 530->88MB, confirmed).
// ---------------------------------------------------------------------------
__global__ __launch_bounds__(256, 2) void fused_score_kernel(
    const unsigned short* __restrict__ A,   // Fh  [M][D] bf16
    const unsigned short* __restrict__ Bt,  // W1T [U][D] bf16
    const float* __restrict__ ph,           // [B][U]
    const float* __restrict__ V,            // [U]
    float* __restrict__ logits) {           // [M] (zero-initialized)
  __shared__ unsigned short As[128 * 32];  // [row][k] rows of 64B
  __shared__ unsigned short Bs[128 * 32];  // [n][k]

  const int tid = threadIdx.x;
  const int wave = tid >> 6;
  const int lane = tid & 63;
  const int l15 = lane & 15;
  const int quad = lane >> 4;
  const int wm = wave >> 1;   // wave row (0..1)
  const int wn = wave & 1;    // wave col (0..1)

  const int i = blockIdx.x;
  const int mtile = ((i >> 6) << 3) + (i & 7);  // 0..511
  const int ntile = (i >> 3) & 7;               // 0..7
  const long m0 = (long)mtile * 128;
  const int n0 = ntile * 128;

  // staging: chunk c covers rows [c*16, c*16+16); lane -> row c*16 + lane/4, k-ofs (lane&3)*8
  const int srow = lane >> 2;
  const int skof = (lane & 3) * 8;
  const int c0 = wave * 2;
  const unsigned short* Ab = A + (m0 + srow) * 1024 + skof;
  const unsigned short* Bb = Bt + ((long)n0 + srow) * 1024 + skof;

  f32x4 acc[4][4];
#pragma unroll
  for (int ii = 0; ii < 4; ++ii)
#pragma unroll
    for (int j = 0; j < 4; ++j) acc[ii][j] = (f32x4){0.f, 0.f, 0.f, 0.f};

  for (int k0 = 0; k0 < 1024; k0 += 32) {
#pragma unroll
    for (int cc = 0; cc < 2; ++cc) {
      const int c = c0 + cc;
      async_copy16(Ab + (long)c * 16 * 1024 + k0, &As[c * 512]);
      async_copy16(Bb + (long)c * 16 * 1024 + k0, &Bs[c * 512]);
    }
    __syncthreads();

    bf16x8 af[4], bf[4];
#pragma unroll
    for (int mi = 0; mi < 4; ++mi)
      af[mi] = *(const bf16x8*)&As[(wm * 64 + mi * 16 + l15) * 32 + quad * 8];
#pragma unroll
    for (int ni = 0; ni < 4; ++ni)
      bf[ni] = *(const bf16x8*)&Bs[(wn * 64 + ni * 16 + l15) * 32 + quad * 8];
#pragma unroll
    for (int mi = 0; mi < 4; ++mi)
#pragma unroll
      for (int ni = 0; ni < 4; ++ni)
        acc[mi][ni] = __builtin_amdgcn_mfma_f32_16x16x32_bf16(
            af[mi], bf[ni], acc[mi][ni], 0, 0, 0);
    __syncthreads();
  }

  // epilogue: s = tanh(acc + ph[b][u]); partial = s*V[u]; reduce over 128 cols
  const int b = (int)(m0 >> 10);  // 128-row tile lies within one batch b
  float phv[4], vv[4];
#pragma unroll
  for (int ni = 0; ni < 4; ++ni) {
    int u = n0 + wn * 64 + ni * 16 + l15;
    phv[ni] = ph[b * U_ + u];
    vv[ni] = V[u];
  }
#pragma unroll
  for (int mi = 0; mi < 4; ++mi) {
#pragma unroll
    for (int r = 0; r < 4; ++r) {
      float part = 0.f;
#pragma unroll
      for (int ni = 0; ni < 4; ++ni) {
        float s = acc[mi][ni][r] + phv[ni];
        float t = __expf(2.0f * s);                       // inf-safe
        float th = 1.0f - 2.0f * __builtin_amdgcn_rcpf(t + 1.0f);
        part += th * vv[ni];
      }
      // C/D layout: col = lane&15 -> sum across the 16-lane group (same quad)
      part += __shfl_xor(part, 1, 16);
      part += __shfl_xor(part, 2, 16);
      part += __shfl_xor(part, 4, 16);
      part += __shfl_xor(part, 8, 16);
      if (l15 == 0)
        atomicAdd(&logits[m0 + wm * 64 + mi * 16 + quad * 4 + r], part);
    }
  }
}

// ---------------------------------------------------------------------------
// Kernel 5: softmax over L per batch (bV is a constant shift -> drops out)
// ---------------------------------------------------------------------------
__global__ __launch_bounds__(256) void softmax_kernel(
    const float* __restrict__ logits, float* __restrict__ wout) {
  __shared__ float redm[4];
  __shared__ float reds[4];
  int b = blockIdx.x;
  int tid = threadIdx.x;
  int wave = tid >> 6, lane = tid & 63;
  float4 v = *(const float4*)&logits[b * 1024 + tid * 4];
  float m = fmaxf(fmaxf(v.x, v.y), fmaxf(v.z, v.w));
#pragma unroll
  for (int off = 32; off >= 1; off >>= 1) m = fmaxf(m, __shfl_xor(m, off, 64));
  if (lane == 0) redm[wave] = m;
  __syncthreads();
  m = fmaxf(fmaxf(redm[0], redm[1]), fmaxf(redm[2], redm[3]));
  float e0 = __expf(v.x - m), e1 = __expf(v.y - m);
  float e2 = __expf(v.z - m), e3 = __expf(v.w - m);
  float s = e0 + e1 + e2 + e3;
#pragma unroll
  for (int off = 32; off >= 1; off >>= 1) s += __shfl_xor(s, off, 64);
  if (lane == 0) reds[wave] = s;
  __syncthreads();
  s = reds[0] + reds[1] + reds[2] + reds[3];
  float inv = 1.0f / s;
  float4 o = {e0 * inv, e1 * inv, e2 * inv, e3 * inv};
  *(float4*)&wout[b * 1024 + tid * 4] = o;
}

// ---------------------------------------------------------------------------
// Kernel 6: context[b][d] = sum_l w[b][l] * Fh[b][l][d]  (bf16 features)
// grid (64 b, 16 l-chunks of 64). 16B/lane loads (ushort8 = 8 d per thread),
// 2 rows in flight per block (256 thr = 2 x 128-thread row groups), unroll 4.
// ---------------------------------------------------------------------------
__global__ __launch_bounds__(256) void context_kernel(
    const unsigned short* __restrict__ Fh, const float* __restrict__ wv,
    float* __restrict__ out) {
  int b = blockIdx.x;
  int l0 = blockIdx.y * 64;
  int half = threadIdx.x >> 7;          // 0..1 (row within pair)
  int d8 = (threadIdx.x & 127) * 8;     // 8 consecutive d per thread
  const unsigned short* fp = Fh + ((long)b * 1024 + l0 + half) * 1024 + d8;
  const float* wp = wv + b * 1024 + l0 + half;
  float acc[8];
#pragma unroll
  for (int j = 0; j < 8; ++j) acc[j] = 0.f;
#pragma unroll 4
  for (int l = 0; l < 64; l += 2) {
    u16x8 f = *(const u16x8*)(fp + (long)l * 1024);
    float w = wp[l];
#pragma unroll
    for (int j = 0; j < 8; ++j) acc[j] += w * bf2f(f[j]);
  }
#pragma unroll
  for (int j = 0; j < 8; ++j) atomicAdd(&out[b * 1024 + d8 + j], acc[j]);
}

// ---------------------------------------------------------------------------
extern "C" void kernel_launch(void* const* d_in, const int* in_sizes, int n_in,
                              void* d_out, int out_size, void* d_ws, size_t ws_size,
                              hipStream_t stream) {
  const float* features = (const float*)d_in[0];  // [64,1024,1024]
  const float* hidden   = (const float*)d_in[1];  // [64,1024]
  const float* W1       = (const float*)d_in[2];  // [1024,1024]
  const float* b1       = (const float*)d_in[3];  // [1024]
  const float* W2       = (const float*)d_in[4];  // [1024,1024]
  const float* b2       = (const float*)d_in[5];  // [1024]
  const float* V        = (const float*)d_in[6];  // [1024]
  // d_in[7] = bV: softmax is shift-invariant, unused.

  char* ws = (char*)d_ws;
  unsigned short* Fh  = (unsigned short*)ws;                          // 128 MB bf16 features
  unsigned short* W1T = (unsigned short*)(ws + 134217728);            // 2 MB bf16 W1^T
  float* ph     = (float*)(ws + 134217728 + 2097152);                 // 256 KB
  float* logits = (float*)(ws + 134217728 + 2097152 + 262144);        // 256 KB
  float* ctx  = (float*)d_out;            // [64,1024]
  float* wout = (float*)d_out + 65536;    // [64,1024] attention weights

  // zero atomic targets (ph+logits contiguous) and context output
  hipMemsetAsync(ph, 0, 262144 + 262144, stream);
  hipMemsetAsync(d_out, 0, 65536 * sizeof(float), stream);

  convert_f_bf16<<<4096, 256, 0, stream>>>((const float4*)features, (u16x8*)Fh);
  transpose_w1<<<dim3(32, 32), 256, 0, stream>>>(W1, W1T);
  proj_h_kernel<<<dim3(4, 8, 8), 256, 0, stream>>>(hidden, W2, b1, b2, ph);
  fused_score_kernel<<<4096, 256, 0, stream>>>(Fh, W1T, ph, V, logits);
  softmax_kernel<<<64, 256, 0, stream>>>(logits, wout);
  context_kernel<<<dim3(64, 16), 256, 0, stream>>>(Fh, wout, ctx);
}

// Round 4
// 623.109 us; speedup vs baseline: 1.0594x; 1.0594x over previous
//
#include <hip/hip_runtime.h>
#include <hip/hip_bf16.h>
#include <stdint.h>

// Problem constants (B,L,D,H,UNITS = 64,1024,1024,1024,1024)
#define B_ 64
#define L_ 1024
#define D_ 1024
#define U_ 1024
#define M_ (B_ * L_)  // 65536 rows of the big GEMM

typedef __attribute__((ext_vector_type(8))) __bf16 bf16x8;
typedef __attribute__((ext_vector_type(4))) float f32x4;
typedef __attribute__((ext_vector_type(8))) unsigned short u16x8;

// fp32 -> bf16 with round-to-nearest-even
__device__ __forceinline__ unsigned short f2bf(float f) {
  unsigned u = __float_as_uint(f);
  unsigned r = (u + 0x7fffu + ((u >> 16) & 1u)) >> 16;
  return (unsigned short)r;
}

__device__ __forceinline__ float bf2f(unsigned short h) {
  return __uint_as_float(((unsigned)h) << 16);
}

// async global->LDS, 16B per lane. LDS dest must be wave-uniform base; HW adds lane*16.
__device__ __forceinline__ void async_copy16(const void* gptr, void* ldsptr) {
  __builtin_amdgcn_global_load_lds(
      (const __attribute__((address_space(1))) void*)gptr,
      (__attribute__((address_space(3))) void*)ldsptr,
      16, 0, 0);
}

// ---------------------------------------------------------------------------
// Kernel 1: features fp32 [M][D] -> bf16 [M][D]
// 8 sweeps, every instruction lane-contiguous (float4 load / ushort4 store),
// 8 independent loads in flight per thread. (R2's 32B-strided pair loads
// touched 2x the cache lines per instruction -- reverted.)
// ---------------------------------------------------------------------------
__global__ __launch_bounds__(256) void convert_f_bf16(
    const float4* __restrict__ src, ushort4* __restrict__ dst) {
  const long stride = 8192L * 256;
  long i = (long)blockIdx.x * 256 + threadIdx.x;
#pragma unroll
  for (int s = 0; s < 8; ++s) {
    float4 v = src[i];
    ushort4 o;
    o.x = f2bf(v.x); o.y = f2bf(v.y); o.z = f2bf(v.z); o.w = f2bf(v.w);
    dst[i] = o;
    i += stride;
  }
}

// ---------------------------------------------------------------------------
// Kernel 2: W1 [D][U] fp32 -> W1T [U][D] bf16 (so B-fragments are K-contiguous)
// ---------------------------------------------------------------------------
__global__ __launch_bounds__(256) void transpose_w1(
    const float* __restrict__ W1, unsigned short* __restrict__ W1T) {
  __shared__ float tile[32][33];
  int tx = threadIdx.x & 31, ty = threadIdx.x >> 5;  // (32,8)
  int u0 = blockIdx.x * 32, k0 = blockIdx.y * 32;
#pragma unroll
  for (int i = ty; i < 32; i += 8) tile[i][tx] = W1[(long)(k0 + i) * U_ + u0 + tx];
  __syncthreads();
#pragma unroll
  for (int i = ty; i < 32; i += 8)
    W1T[(long)(u0 + i) * D_ + k0 + tx] = f2bf(tile[tx][i]);
}

// ---------------------------------------------------------------------------
// Kernel 3: ph[b][u] = hidden[b][:] @ W2[:][u] + b1[u] + b2[u]   (fp32 exact)
// grid (4 u-tiles, 8 b-groups, 8 h-chunks), atomicAdd into zeroed ph
// (R1 form -- part of the measured 597us baseline)
// ---------------------------------------------------------------------------
__global__ __launch_bounds__(256) void proj_h_kernel(
    const float* __restrict__ hidden, const float* __restrict__ W2,
    const float* __restrict__ b1, const float* __restrict__ b2,
    float* __restrict__ ph) {
  int u = blockIdx.x * 256 + threadIdx.x;
  int bbase = blockIdx.y * 8;
  int h0 = blockIdx.z * 128;
  float acc[8];
  float bias = (blockIdx.z == 0) ? (b1[u] + b2[u]) : 0.0f;
#pragma unroll
  for (int i = 0; i < 8; ++i) acc[i] = bias;
#pragma unroll 4
  for (int h = h0; h < h0 + 128; ++h) {
    float w = W2[(long)h * U_ + u];
#pragma unroll
    for (int i = 0; i < 8; ++i) acc[i] += hidden[(bbase + i) * 1024 + h] * w;
  }
#pragma unroll
  for (int i = 0; i < 8; ++i) atomicAdd(&ph[(bbase + i) * U_ + u], acc[i]);
}

// ---------------------------------------------------------------------------
// Kernel 4: fused  logits[m] += sum_u tanh(A@W1 + ph) * V[u]
// m97 structure: 128x128 tile, BK=32, 4 waves (2x2), 4x4 16x16x32 MFMA per wave,
// global_load_lds dwordx4 staging, unpadded [row][k] LDS tiles.
// 1D grid 4096 with XCD-aware decode (R1: FETCH 530->88MB, confirmed).
// ---------------------------------------------------------------------------
__global__ __launch_bounds__(256, 2) void fused_score_kernel(
    const unsigned short* __restrict__ A,   // Fh  [M][D] bf16
    const unsigned short* __restrict__ Bt,  // W1T [U][D] bf16
    const float* __restrict__ ph,           // [B][U]
    const float* __restrict__ V,            // [U]
    float* __restrict__ logits) {           // [M] (zero-initialized)
  __shared__ unsigned short As[128 * 32];  // [row][k] rows of 64B
  __shared__ unsigned short Bs[128 * 32];  // [n][k]

  const int tid = threadIdx.x;
  const int wave = tid >> 6;
  const int lane = tid & 63;
  const int l15 = lane & 15;
  const int quad = lane >> 4;
  const int wm = wave >> 1;   // wave row (0..1)
  const int wn = wave & 1;    // wave col (0..1)

  const int i = blockIdx.x;
  const int mtile = ((i >> 6) << 3) + (i & 7);  // 0..511
  const int ntile = (i >> 3) & 7;               // 0..7
  const long m0 = (long)mtile * 128;
  const int n0 = ntile * 128;

  // staging: chunk c covers rows [c*16, c*16+16); lane -> row c*16 + lane/4, k-ofs (lane&3)*8
  const int srow = lane >> 2;
  const int skof = (lane & 3) * 8;
  const int c0 = wave * 2;
  const unsigned short* Ab = A + (m0 + srow) * 1024 + skof;
  const unsigned short* Bb = Bt + ((long)n0 + srow) * 1024 + skof;

  f32x4 acc[4][4];
#pragma unroll
  for (int ii = 0; ii < 4; ++ii)
#pragma unroll
    for (int j = 0; j < 4; ++j) acc[ii][j] = (f32x4){0.f, 0.f, 0.f, 0.f};

  for (int k0 = 0; k0 < 1024; k0 += 32) {
#pragma unroll
    for (int cc = 0; cc < 2; ++cc) {
      const int c = c0 + cc;
      async_copy16(Ab + (long)c * 16 * 1024 + k0, &As[c * 512]);
      async_copy16(Bb + (long)c * 16 * 1024 + k0, &Bs[c * 512]);
    }
    __syncthreads();

    bf16x8 af[4], bf[4];
#pragma unroll
    for (int mi = 0; mi < 4; ++mi)
      af[mi] = *(const bf16x8*)&As[(wm * 64 + mi * 16 + l15) * 32 + quad * 8];
#pragma unroll
    for (int ni = 0; ni < 4; ++ni)
      bf[ni] = *(const bf16x8*)&Bs[(wn * 64 + ni * 16 + l15) * 32 + quad * 8];
#pragma unroll
    for (int mi = 0; mi < 4; ++mi)
#pragma unroll
      for (int ni = 0; ni < 4; ++ni)
        acc[mi][ni] = __builtin_amdgcn_mfma_f32_16x16x32_bf16(
            af[mi], bf[ni], acc[mi][ni], 0, 0, 0);
    __syncthreads();
  }

  // epilogue: s = tanh(acc + ph[b][u]); partial = s*V[u]; reduce over 128 cols
  const int b = (int)(m0 >> 10);  // 128-row tile lies within one batch b
  float phv[4], vv[4];
#pragma unroll
  for (int ni = 0; ni < 4; ++ni) {
    int u = n0 + wn * 64 + ni * 16 + l15;
    phv[ni] = ph[b * U_ + u];
    vv[ni] = V[u];
  }
#pragma unroll
  for (int mi = 0; mi < 4; ++mi) {
#pragma unroll
    for (int r = 0; r < 4; ++r) {
      float part = 0.f;
#pragma unroll
      for (int ni = 0; ni < 4; ++ni) {
        float s = acc[mi][ni][r] + phv[ni];
        float t = __expf(2.0f * s);                       // inf-safe
        float th = 1.0f - 2.0f * __builtin_amdgcn_rcpf(t + 1.0f);
        part += th * vv[ni];
      }
      // C/D layout: col = lane&15 -> sum across the 16-lane group (same quad)
      part += __shfl_xor(part, 1, 16);
      part += __shfl_xor(part, 2, 16);
      part += __shfl_xor(part, 4, 16);
      part += __shfl_xor(part, 8, 16);
      if (l15 == 0)
        atomicAdd(&logits[m0 + wm * 64 + mi * 16 + quad * 4 + r], part);
    }
  }
}

// ---------------------------------------------------------------------------
// Kernel 5: softmax over L per batch (bV is a constant shift -> drops out)
// ---------------------------------------------------------------------------
__global__ __launch_bounds__(256) void softmax_kernel(
    const float* __restrict__ logits, float* __restrict__ wout) {
  __shared__ float redm[4];
  __shared__ float reds[4];
  int b = blockIdx.x;
  int tid = threadIdx.x;
  int wave = tid >> 6, lane = tid & 63;
  float4 v = *(const float4*)&logits[b * 1024 + tid * 4];
  float m = fmaxf(fmaxf(v.x, v.y), fmaxf(v.z, v.w));
#pragma unroll
  for (int off = 32; off >= 1; off >>= 1) m = fmaxf(m, __shfl_xor(m, off, 64));
  if (lane == 0) redm[wave] = m;
  __syncthreads();
  m = fmaxf(fmaxf(redm[0], redm[1]), fmaxf(redm[2], redm[3]));
  float e0 = __expf(v.x - m), e1 = __expf(v.y - m);
  float e2 = __expf(v.z - m), e3 = __expf(v.w - m);
  float s = e0 + e1 + e2 + e3;
#pragma unroll
  for (int off = 32; off >= 1; off >>= 1) s += __shfl_xor(s, off, 64);
  if (lane == 0) reds[wave] = s;
  __syncthreads();
  s = reds[0] + reds[1] + reds[2] + reds[3];
  float inv = 1.0f / s;
  float4 o = {e0 * inv, e1 * inv, e2 * inv, e3 * inv};
  *(float4*)&wout[b * 1024 + tid * 4] = o;
}

// ---------------------------------------------------------------------------
// Kernel 6: context[b][d] = sum_l w[b][l] * Fh[b][l][d]  (bf16 features)
// grid (64 b, 8 l-chunks of 128). 16B/lane loads (ushort8 = 8 d/thread);
// 2 row-halves per block (128 threads each), combined via LDS before the
// atomic -> atomic count stays at 512K total (8/address), same as the
// 597us-measured R1 baseline, but with double load width + unroll-4 ILP.
// ---------------------------------------------------------------------------
__global__ __launch_bounds__(256) void context_kernel(
    const unsigned short* __restrict__ Fh, const float* __restrict__ wv,
    float* __restrict__ out) {
  __shared__ float red[128][8];
  int b = blockIdx.x;
  int l0 = blockIdx.y * 128;
  int half = threadIdx.x >> 7;       // 0..1 (even/odd rows)
  int t = threadIdx.x & 127;
  int d8 = t * 8;                    // 8 consecutive d per thread, 128 thr = full row
  const unsigned short* fp = Fh + ((long)b * 1024 + l0 + half) * 1024 + d8;
  const float* wp = wv + b * 1024 + l0 + half;
  float acc[8];
#pragma unroll
  for (int j = 0; j < 8; ++j) acc[j] = 0.f;
#pragma unroll 4
  for (int l = 0; l < 128; l += 2) {
    u16x8 f = *(const u16x8*)(fp + (long)l * 1024);
    float w = wp[l];
#pragma unroll
    for (int j = 0; j < 8; ++j) acc[j] += w * bf2f(f[j]);
  }
  if (half) {
#pragma unroll
    for (int j = 0; j < 8; ++j) red[t][j] = acc[j];
  }
  __syncthreads();
  if (!half) {
#pragma unroll
    for (int j = 0; j < 8; ++j)
      atomicAdd(&out[b * 1024 + d8 + j], acc[j] + red[t][j]);
  }
}

// ---------------------------------------------------------------------------
extern "C" void kernel_launch(void* const* d_in, const int* in_sizes, int n_in,
                              void* d_out, int out_size, void* d_ws, size_t ws_size,
                              hipStream_t stream) {
  const float* features = (const float*)d_in[0];  // [64,1024,1024]
  const float* hidden   = (const float*)d_in[1];  // [64,1024]
  const float* W1       = (const float*)d_in[2];  // [1024,1024]
  const float* b1       = (const float*)d_in[3];  // [1024]
  const float* W2       = (const float*)d_in[4];  // [1024,1024]
  const float* b2       = (const float*)d_in[5];  // [1024]
  const float* V        = (const float*)d_in[6];  // [1024]
  // d_in[7] = bV: softmax is shift-invariant, unused.

  char* ws = (char*)d_ws;
  unsigned short* Fh  = (unsigned short*)ws;                          // 128 MB bf16 features
  unsigned short* W1T = (unsigned short*)(ws + 134217728);            // 2 MB bf16 W1^T
  float* ph     = (float*)(ws + 134217728 + 2097152);                 // 256 KB
  float* logits = (float*)(ws + 134217728 + 2097152 + 262144);        // 256 KB
  float* ctx  = (float*)d_out;            // [64,1024]
  float* wout = (float*)d_out + 65536;    // [64,1024] attention weights

  // zero atomic targets (ph+logits contiguous) and context output
  hipMemsetAsync(ph, 0, 262144 + 262144, stream);
  hipMemsetAsync(d_out, 0, 65536 * sizeof(float), stream);

  convert_f_bf16<<<8192, 256, 0, stream>>>((const float4*)features, (ushort4*)Fh);
  transpose_w1<<<dim3(32, 32), 256, 0, stream>>>(W1, W1T);
  proj_h_kernel<<<dim3(4, 8, 8), 256, 0, stream>>>(hidden, W2, b1, b2, ph);
  fused_score_kernel<<<4096, 256, 0, stream>>>(Fh, W1T, ph, V, logits);
  softmax_kernel<<<64, 256, 0, stream>>>(logits, wout);
  context_kernel<<<dim3(64, 8), 256, 0, stream>>>(Fh, wout, ctx);
}

// Round 5
// 595.291 us; speedup vs baseline: 1.1090x; 1.0467x over previous
//
#include <hip/hip_runtime.h>
#include <hip/hip_bf16.h>
#include <stdint.h>

// Problem constants (B,L,D,H,UNITS = 64,1024,1024,1024,1024)
#define B_ 64
#define L_ 1024
#define D_ 1024
#define U_ 1024
#define M_ (B_ * L_)  // 65536 rows of the big GEMM

// K-dimension LDS-bank swizzle: within each 32-element k-group, the four 16B
// chunks are stored XOR-permuted by ((row>>1)&3). Involutive; 32-aligned tiles
// keep it consistent between producers (convert/transpose), the GEMM fragment
// reads, and context's unswizzled consumption.
__device__ __forceinline__ int swz_k(int k, int row) {
  return (k & ~31) | (((((k >> 3) & 3) ^ ((row >> 1) & 3))) << 3) | (k & 7);
}

typedef __attribute__((ext_vector_type(8))) __bf16 bf16x8;
typedef __attribute__((ext_vector_type(4))) float f32x4;
typedef __attribute__((ext_vector_type(8))) unsigned short u16x8;

// fp32 -> bf16 with round-to-nearest-even
__device__ __forceinline__ unsigned short f2bf(float f) {
  unsigned u = __float_as_uint(f);
  unsigned r = (u + 0x7fffu + ((u >> 16) & 1u)) >> 16;
  return (unsigned short)r;
}

__device__ __forceinline__ float bf2f(unsigned short h) {
  return __uint_as_float(((unsigned)h) << 16);
}

// async global->LDS, 16B per lane. LDS dest must be wave-uniform base; HW adds lane*16.
__device__ __forceinline__ void async_copy16(const void* gptr, void* ldsptr) {
  __builtin_amdgcn_global_load_lds(
      (const __attribute__((address_space(1))) void*)gptr,
      (__attribute__((address_space(3))) void*)ldsptr,
      16, 0, 0);
}

// ---------------------------------------------------------------------------
// Kernel 1: features fp32 [M][D] -> bf16 [M][D], K-swizzled (R1 form + swizzle)
// ---------------------------------------------------------------------------
__global__ __launch_bounds__(256) void convert_f_bf16(
    const float4* __restrict__ src, ushort4* __restrict__ dst) {
  long i = (long)blockIdx.x * 256 + threadIdx.x;  // float4 index
  float4 v = src[i];
  ushort4 o;
  o.x = f2bf(v.x); o.y = f2bf(v.y); o.z = f2bf(v.z); o.w = f2bf(v.w);
  int m = (int)(i >> 8);            // 256 float4 per row
  int k4 = (int)(i & 255) << 2;     // 0..1020, step 4 (within one 16B chunk half)
  int kp = swz_k(k4, m);
  dst[(((long)m << 10) + kp) >> 2] = o;
}

// ---------------------------------------------------------------------------
// Kernel 2: W1 [D][U] fp32 -> W1T [U][D] bf16, K-swizzled
// ---------------------------------------------------------------------------
__global__ __launch_bounds__(256) void transpose_w1(
    const float* __restrict__ W1, unsigned short* __restrict__ W1T) {
  __shared__ float tile[32][33];
  int tx = threadIdx.x & 31, ty = threadIdx.x >> 5;  // (32,8)
  int u0 = blockIdx.x * 32, k0 = blockIdx.y * 32;
#pragma unroll
  for (int i = ty; i < 32; i += 8) tile[i][tx] = W1[(long)(k0 + i) * U_ + u0 + tx];
  __syncthreads();
#pragma unroll
  for (int i = ty; i < 32; i += 8) {
    int u = u0 + i, k = k0 + tx;
    W1T[(long)u * D_ + swz_k(k, u)] = f2bf(tile[tx][i]);
  }
}

// ---------------------------------------------------------------------------
// Kernel 3: ph[b][u] = hidden[b][:] @ W2[:][u] + b1[u] + b2[u]   (fp32 exact)
// R1 exact form (measured-best).
// ---------------------------------------------------------------------------
__global__ __launch_bounds__(256) void proj_h_kernel(
    const float* __restrict__ hidden, const float* __restrict__ W2,
    const float* __restrict__ b1, const float* __restrict__ b2,
    float* __restrict__ ph) {
  int u = blockIdx.x * 256 + threadIdx.x;
  int bbase = blockIdx.y * 8;
  int h0 = blockIdx.z * 128;
  float acc[8];
  float bias = (blockIdx.z == 0) ? (b1[u] + b2[u]) : 0.0f;
#pragma unroll
  for (int i = 0; i < 8; ++i) acc[i] = bias;
  for (int h = h0; h < h0 + 128; ++h) {
    float w = W2[(long)h * U_ + u];
#pragma unroll
    for (int i = 0; i < 8; ++i) acc[i] += hidden[(bbase + i) * 1024 + h] * w;
  }
#pragma unroll
  for (int i = 0; i < 8; ++i) atomicAdd(&ph[(bbase + i) * U_ + u], acc[i]);
}

// ---------------------------------------------------------------------------
// Kernel 4: fused  logits[m] += sum_u tanh(A@W1 + ph) * V[u]
// m97 structure + XCD swizzle (R1) + K-swizzled LDS reads (this round):
// fragment col = (quad ^ ((l15>>1)&3))*8 -> 2 lanes/bank-group (free) instead
// of 8-way conflicts (SQ_LDS_BANK_CONFLICT 1.678e7 ~= 27us/CU of LDS stall).
// ---------------------------------------------------------------------------
__global__ __launch_bounds__(256, 2) void fused_score_kernel(
    const unsigned short* __restrict__ A,   // Fh  [M][D] bf16, K-swizzled
    const unsigned short* __restrict__ Bt,  // W1T [U][D] bf16, K-swizzled
    const float* __restrict__ ph,           // [B][U]
    const float* __restrict__ V,            // [U]
    float* __restrict__ logits) {           // [M] (zero-initialized)
  __shared__ unsigned short As[128 * 32];  // [row][k] rows of 64B
  __shared__ unsigned short Bs[128 * 32];  // [n][k]

  const int tid = threadIdx.x;
  const int wave = tid >> 6;
  const int lane = tid & 63;
  const int l15 = lane & 15;
  const int quad = lane >> 4;
  const int wm = wave >> 1;   // wave row (0..1)
  const int wn = wave & 1;    // wave col (0..1)
  const int xk = (l15 >> 1) & 3;  // swizzle term: (row>>1)&3 with 128-aligned m0/n0

  const int i = blockIdx.x;
  const int mtile = ((i >> 6) << 3) + (i & 7);  // 0..511
  const int ntile = (i >> 3) & 7;               // 0..7
  const long m0 = (long)mtile * 128;
  const int n0 = ntile * 128;

  // staging: chunk c covers rows [c*16, c*16+16); lane -> row c*16 + lane/4, k-ofs (lane&3)*8
  const int srow = lane >> 2;
  const int skof = (lane & 3) * 8;
  const int c0 = wave * 2;
  const unsigned short* Ab = A + (m0 + srow) * 1024 + skof;
  const unsigned short* Bb = Bt + ((long)n0 + srow) * 1024 + skof;

  f32x4 acc[4][4];
#pragma unroll
  for (int ii = 0; ii < 4; ++ii)
#pragma unroll
    for (int j = 0; j < 4; ++j) acc[ii][j] = (f32x4){0.f, 0.f, 0.f, 0.f};

  for (int k0 = 0; k0 < 1024; k0 += 32) {
#pragma unroll
    for (int cc = 0; cc < 2; ++cc) {
      const int c = c0 + cc;
      async_copy16(Ab + (long)c * 16 * 1024 + k0, &As[c * 512]);
      async_copy16(Bb + (long)c * 16 * 1024 + k0, &Bs[c * 512]);
    }
    __syncthreads();

    bf16x8 af[4], bf[4];
#pragma unroll
    for (int mi = 0; mi < 4; ++mi)
      af[mi] = *(const bf16x8*)&As[(wm * 64 + mi * 16 + l15) * 32 + ((quad ^ xk) << 3)];
#pragma unroll
    for (int ni = 0; ni < 4; ++ni)
      bf[ni] = *(const bf16x8*)&Bs[(wn * 64 + ni * 16 + l15) * 32 + ((quad ^ xk) << 3)];
#pragma unroll
    for (int mi = 0; mi < 4; ++mi)
#pragma unroll
      for (int ni = 0; ni < 4; ++ni)
        acc[mi][ni] = __builtin_amdgcn_mfma_f32_16x16x32_bf16(
            af[mi], bf[ni], acc[mi][ni], 0, 0, 0);
    __syncthreads();
  }

  // epilogue: s = tanh(acc + ph[b][u]); partial = s*V[u]; reduce over 128 cols
  const int b = (int)(m0 >> 10);  // 128-row tile lies within one batch b
  float phv[4], vv[4];
#pragma unroll
  for (int ni = 0; ni < 4; ++ni) {
    int u = n0 + wn * 64 + ni * 16 + l15;
    phv[ni] = ph[b * U_ + u];
    vv[ni] = V[u];
  }
#pragma unroll
  for (int mi = 0; mi < 4; ++mi) {
#pragma unroll
    for (int r = 0; r < 4; ++r) {
      float part = 0.f;
#pragma unroll
      for (int ni = 0; ni < 4; ++ni) {
        float s = acc[mi][ni][r] + phv[ni];
        float t = __expf(2.0f * s);                       // inf-safe
        float th = 1.0f - 2.0f * __builtin_amdgcn_rcpf(t + 1.0f);
        part += th * vv[ni];
      }
      // C/D layout: col = lane&15 -> sum across the 16-lane group (same quad)
      part += __shfl_xor(part, 1, 16);
      part += __shfl_xor(part, 2, 16);
      part += __shfl_xor(part, 4, 16);
      part += __shfl_xor(part, 8, 16);
      if (l15 == 0)
        atomicAdd(&logits[m0 + wm * 64 + mi * 16 + quad * 4 + r], part);
    }
  }
}

// ---------------------------------------------------------------------------
// Kernel 5: softmax over L per batch (bV is a constant shift -> drops out)
// ---------------------------------------------------------------------------
__global__ __launch_bounds__(256) void softmax_kernel(
    const float* __restrict__ logits, float* __restrict__ wout) {
  __shared__ float redm[4];
  __shared__ float reds[4];
  int b = blockIdx.x;
  int tid = threadIdx.x;
  int wave = tid >> 6, lane = tid & 63;
  float4 v = *(const float4*)&logits[b * 1024 + tid * 4];
  float m = fmaxf(fmaxf(v.x, v.y), fmaxf(v.z, v.w));
#pragma unroll
  for (int off = 32; off >= 1; off >>= 1) m = fmaxf(m, __shfl_xor(m, off, 64));
  if (lane == 0) redm[wave] = m;
  __syncthreads();
  m = fmaxf(fmaxf(redm[0], redm[1]), fmaxf(redm[2], redm[3]));
  float e0 = __expf(v.x - m), e1 = __expf(v.y - m);
  float e2 = __expf(v.z - m), e3 = __expf(v.w - m);
  float s = e0 + e1 + e2 + e3;
#pragma unroll
  for (int off = 32; off >= 1; off >>= 1) s += __shfl_xor(s, off, 64);
  if (lane == 0) reds[wave] = s;
  __syncthreads();
  s = reds[0] + reds[1] + reds[2] + reds[3];
  float inv = 1.0f / s;
  float4 o = {e0 * inv, e1 * inv, e2 * inv, e3 * inv};
  *(float4*)&wout[b * 1024 + tid * 4] = o;
}

// ---------------------------------------------------------------------------
// Kernel 6: context[b][d] = sum_l w[b][l] * Fh[b][l][d]  (bf16, K-swizzled:
// unswizzle per row on load; out indexed by original d). R1 form otherwise.
// ---------------------------------------------------------------------------
__global__ __launch_bounds__(256) void context_kernel(
    const unsigned short* __restrict__ Fh, const float* __restrict__ wv,
    float* __restrict__ out) {
  int b = blockIdx.x;
  int d4 = threadIdx.x * 4;
  int l0 = blockIdx.y * 128;
  const int hi = d4 & ~31, ch = (d4 >> 3) & 3, off = d4 & 7;
  const unsigned short* fp = Fh + ((long)b * 1024 + l0) * 1024;
  const float* wp = wv + b * 1024 + l0;
  float a0 = 0.f, a1 = 0.f, a2 = 0.f, a3 = 0.f;
#pragma unroll 4
  for (int l = 0; l < 128; ++l) {
    int xr = ((l0 + l) >> 1) & 3;
    ushort4 f = *(const ushort4*)(fp + (long)l * 1024 + hi + ((ch ^ xr) << 3) + off);
    float w = wp[l];
    a0 += w * bf2f(f.x);
    a1 += w * bf2f(f.y);
    a2 += w * bf2f(f.z);
    a3 += w * bf2f(f.w);
  }
  atomicAdd(&out[b * 1024 + d4 + 0], a0);
  atomicAdd(&out[b * 1024 + d4 + 1], a1);
  atomicAdd(&out[b * 1024 + d4 + 2], a2);
  atomicAdd(&out[b * 1024 + d4 + 3], a3);
}

// ---------------------------------------------------------------------------
extern "C" void kernel_launch(void* const* d_in, const int* in_sizes, int n_in,
                              void* d_out, int out_size, void* d_ws, size_t ws_size,
                              hipStream_t stream) {
  const float* features = (const float*)d_in[0];  // [64,1024,1024]
  const float* hidden   = (const float*)d_in[1];  // [64,1024]
  const float* W1       = (const float*)d_in[2];  // [1024,1024]
  const float* b1       = (const float*)d_in[3];  // [1024]
  const float* W2       = (const float*)d_in[4];  // [1024,1024]
  const float* b2       = (const float*)d_in[5];  // [1024]
  const float* V        = (const float*)d_in[6];  // [1024]
  // d_in[7] = bV: softmax is shift-invariant, unused.

  char* ws = (char*)d_ws;
  unsigned short* Fh  = (unsigned short*)ws;                          // 128 MB bf16 features (K-swizzled)
  unsigned short* W1T = (unsigned short*)(ws + 134217728);            // 2 MB bf16 W1^T (K-swizzled)
  float* ph     = (float*)(ws + 134217728 + 2097152);                 // 256 KB
  float* logits = (float*)(ws + 134217728 + 2097152 + 262144);        // 256 KB
  float* ctx  = (float*)d_out;            // [64,1024]
  float* wout = (float*)d_out + 65536;    // [64,1024] attention weights

  // zero atomic targets (ph+logits contiguous) and context output
  hipMemsetAsync(ph, 0, 262144 + 262144, stream);
  hipMemsetAsync(d_out, 0, 65536 * sizeof(float), stream);

  convert_f_bf16<<<65536, 256, 0, stream>>>((const float4*)features, (ushort4*)Fh);
  transpose_w1<<<dim3(32, 32), 256, 0, stream>>>(W1, W1T);
  proj_h_kernel<<<dim3(4, 8, 8), 256, 0, stream>>>(hidden, W2, b1, b2, ph);
  fused_score_kernel<<<4096, 256, 0, stream>>>(Fh, W1T, ph, V, logits);
  softmax_kernel<<<64, 256, 0, stream>>>(logits, wout);
  context_kernel<<<dim3(64, 8), 256, 0, stream>>>(Fh, wout, ctx);
}